// Round 1
// baseline (191.962 us; speedup 1.0000x reference)
//
#include <hip/hip_runtime.h>
#include <hip/hip_cooperative_groups.h>
#include <stdint.h>

namespace cg = cooperative_groups;

typedef unsigned int u32;
typedef unsigned long long u64;

#define TOPK 9
#define GA 64            // anchor grid: 64x64 cells of 16px
#define CELL_A 16.0f
#define NCA (GA * GA)    // 4096
#define GG 16            // GT grid: 16x16 cells of 64px
#define CELL_G 64.0f
#define NCG (GG * GG)    // 256
#define CAPA 96          // anchor bucket capacity (lambda~29, max~56 at N=120k)
#define CAPG 160         // GT bucket capacity (lambda~8)
#define OVA 8192         // anchor overflow list capacity (exactness net)
#define OVG 1024         // GT overflow list capacity

// ===========================================================================
// Single cooperative kernel: zero -> insert -> query -> assign, separated by
// grid.sync(). Phase bodies are verbatim from the 4-dispatch version that
// passed with absmax 0; only the launch structure changed (4 nodes -> 1).
// ===========================================================================
__global__ __launch_bounds__(256) void atss_fused(
    const float4* __restrict__ a4, const float4* __restrict__ g4,
    u32* __restrict__ w, float* __restrict__ outp, int N, int M)
{
    cg::grid_group grid = cg::this_grid();

    // ---- workspace layout (mirrors kernel_launch) ----
    const size_t oCursA  = 0;
    const size_t oCursG  = oCursA + NCA;
    const size_t oOvfCnt = oCursG + NCG;
    const size_t oThresh = oOvfCnt + 2;
    size_t oBkCtr = oThresh + (size_t)M;
    oBkCtr = (oBkCtr + 1) & ~(size_t)1;                // 8B align for float2
    const size_t oBkIdx  = oBkCtr + 2 * (size_t)NCA * CAPA;
    const size_t oGtBkt  = oBkIdx + (size_t)NCA * CAPA;
    const size_t oOvAidx = oGtBkt + (size_t)NCG * CAPG;
    size_t oOvActr = oOvAidx + OVA;
    oOvActr = (oOvActr + 1) & ~(size_t)1;              // 8B align
    const size_t oOvGidx = oOvActr + 2 * (size_t)OVA;

    u32* cursA     = w + oCursA;
    u32* cursG     = w + oCursG;
    u32* ovfCnt    = w + oOvfCnt;
    float* thresh  = (float*)(w + oThresh);
    float2* bkCtr  = (float2*)(w + oBkCtr);
    u32* bkIdx     = w + oBkIdx;
    u32* gtBkt     = w + oGtBkt;
    u32* ovAidx    = w + oOvAidx;
    float2* ovActr = (float2*)(w + oOvActr);
    u32* ovGidx    = w + oOvGidx;
    const float* gts = (const float*)g4;
    float* out_idx = outp;
    float* out_iou = outp + N;

    const int gtid = blockIdx.x * 256 + (int)threadIdx.x;
    const int gstride = (int)gridDim.x * 256;

    // ================= phase 0: zero cursors + overflow counters ============
    for (int i = gtid; i < NCA + NCG + 2; i += gstride) w[i] = 0u;

    grid.sync();

    // ================= phase 1: direct bucket insert ========================
    for (int gid = gtid; gid < N + M; gid += gstride) {
        if (gid < N) {
            float4 a = a4[gid];
            float cx = (a.x + a.z) * 0.5f;
            float cy = (a.y + a.w) * 0.5f;
            int ix = min(GA - 1, max(0, (int)(cx * (1.0f / CELL_A))));
            int iy = min(GA - 1, max(0, (int)(cy * (1.0f / CELL_A))));
            int cell = iy * GA + ix;
            u32 p = atomicAdd(&cursA[cell], 1u);
            if (p < CAPA) {
                bkCtr[cell * CAPA + p] = make_float2(cx, cy);
                bkIdx[cell * CAPA + p] = (u32)gid;
            } else {
                u32 q = atomicAdd(&ovfCnt[0], 1u);
                if (q < OVA) { ovAidx[q] = (u32)gid; ovActr[q] = make_float2(cx, cy); }
            }
        } else {
            int m = gid - N;
            float4 g = g4[m];
            int ix0 = min(GG - 1, max(0, (int)floorf(g.x * (1.0f / CELL_G))));
            int iy0 = min(GG - 1, max(0, (int)floorf(g.y * (1.0f / CELL_G))));
            int ix1 = min(GG - 1, max(0, (int)floorf(g.z * (1.0f / CELL_G))));
            int iy1 = min(GG - 1, max(0, (int)floorf(g.w * (1.0f / CELL_G))));
            for (int j = iy0; j <= iy1; ++j)
                for (int i = ix0; i <= ix1; ++i) {
                    int cell = j * GG + i;
                    u32 p = atomicAdd(&cursG[cell], 1u);
                    if (p < CAPG) gtBkt[cell * CAPG + p] = (u32)m;
                    else {
                        u32 q = atomicAdd(&ovfCnt[1], 1u);
                        if (q < OVG) ovGidx[q] = (u32)m;
                    }
                }
        }
    }

    grid.sync();

    // ================= phase 2: per-GT query (one wave per GT) ==============
    {
        const int lane = threadIdx.x & 63;
        for (int m = (gtid >> 6); m < M; m += (gstride >> 6)) {
            const float gx0 = gts[m * 4 + 0], gy0 = gts[m * 4 + 1];
            const float gx1 = gts[m * 4 + 2], gy1 = gts[m * 4 + 3];
            const float gcx = (gx0 + gx1) * 0.5f;
            const float gcy = (gy0 + gy1) * 0.5f;
            const int ci = min(GA - 1, max(0, (int)(gcx * (1.0f / CELL_A))));
            const int cj = min(GA - 1, max(0, (int)(gcy * (1.0f / CELL_A))));

            // ---- stage 1: expand Chebyshev rings until >=9 anchors counted.
            u32 cum = 0;
            float maxd2 = 0.f;
            for (int r = 0; r < GA && cum < TOPK; ++r) {
                int ncell = (r == 0) ? 1 : 8 * r;
                u32 myc = 0;
                float mymax = 0.f;
                for (int k = lane; k < ncell; k += 64) {
                    int di = 0, dj = 0;
                    if (r > 0) {
                        int side = k / (2 * r), pos = k % (2 * r);
                        if (side == 0)      { di = -r + pos; dj = -r; }
                        else if (side == 1) { di = r;        dj = -r + pos; }
                        else if (side == 2) { di = r - pos;  dj = r; }
                        else                { di = -r;       dj = r - pos; }
                    }
                    int i = ci + di, j = cj + dj;
                    if (i < 0 || i >= GA || j < 0 || j >= GA) continue;
                    u32 cnt = cursA[j * GA + i];
                    if (cnt) {
                        myc += cnt;
                        float x0 = i * CELL_A, x1 = x0 + CELL_A;
                        float y0 = j * CELL_A, y1 = y0 + CELL_A;
                        float dxm = fmaxf(gcx - x0, x1 - gcx);
                        float dym = fmaxf(gcy - y0, y1 - gcy);
                        mymax = fmaxf(mymax, dxm * dxm + dym * dym);
                    }
                }
#pragma unroll
                for (int s2 = 1; s2 <= 32; s2 <<= 1) {
                    myc += __shfl_xor(myc, s2, 64);
                    mymax = fmaxf(mymax, __shfl_xor(mymax, s2, 64));
                }
                cum += myc;
                maxd2 = fmaxf(maxd2, mymax);
            }
            const float D2pad = maxd2 * 1.0001f + 1.0f;  // absorbs fp rounding + sqrt ties

            // ---- stage 2: exact top-9 over bucket slots (+ overflow).
            u64 kk[TOPK];
#pragma unroll
            for (int i = 0; i < TOPK; ++i) kk[i] = ~0ULL;

            const int rs = 1 + (int)(sqrtf(D2pad) * (1.0f / CELL_A));
            const int jlo = max(0, cj - rs), jhi = min(GA - 1, cj + rs);
            const int ilo = max(0, ci - rs), ihi = min(GA - 1, ci + rs);
            for (int j = jlo; j <= jhi; ++j) {
                float y0 = j * CELL_A, y1 = y0 + CELL_A;
                float mdy = fmaxf(fmaxf(y0 - gcy, gcy - y1), 0.f);
                for (int i = ilo; i <= ihi; ++i) {
                    float x0 = i * CELL_A, x1 = x0 + CELL_A;
                    float mdx = fmaxf(fmaxf(x0 - gcx, gcx - x1), 0.f);
                    if (mdx * mdx + mdy * mdy > D2pad) continue;
                    int c = j * GA + i;
                    u32 cnt = min(cursA[c], (u32)CAPA);
                    u32 base = (u32)c * CAPA;
                    for (u32 tc = lane; tc < cnt; tc += 64) {
                        u32 n = bkIdx[base + tc];
                        float2 cc = bkCtr[base + tc];
                        float ddx = cc.x - gcx, ddy = cc.y - gcy;
                        float d2 = ddx * ddx + ddy * ddy;
                        if (d2 <= D2pad) {
                            float d = sqrtf(d2);
                            u64 key = ((u64)__float_as_uint(d) << 32) | n;
                            if (key < kk[TOPK - 1]) {
                                u64 t2 = key;
#pragma unroll
                                for (int q = 0; q < TOPK; ++q) {
                                    u64 lo = (kk[q] < t2) ? kk[q] : t2;
                                    u64 hi = (kk[q] < t2) ? t2 : kk[q];
                                    kk[q] = lo;
                                    t2 = hi;
                                }
                            }
                        }
                    }
                }
            }
            {   // overflow anchors (exactness net; count is 0 on this data)
                u32 nov = min(ovfCnt[0], (u32)OVA);
                for (u32 tc = lane; tc < nov; tc += 64) {
                    u32 n = ovAidx[tc];
                    float2 cc = ovActr[tc];
                    float ddx = cc.x - gcx, ddy = cc.y - gcy;
                    float d2 = ddx * ddx + ddy * ddy;
                    if (d2 <= D2pad) {
                        float d = sqrtf(d2);
                        u64 key = ((u64)__float_as_uint(d) << 32) | n;
                        if (key < kk[TOPK - 1]) {
                            u64 t2 = key;
#pragma unroll
                            for (int q = 0; q < TOPK; ++q) {
                                u64 lo = (kk[q] < t2) ? kk[q] : t2;
                                u64 hi = (kk[q] < t2) ? t2 : kk[q];
                                kk[q] = lo;
                                t2 = hi;
                            }
                        }
                    }
                }
            }

            // ---- wave merge: 9 pop-min rounds (u64 butterfly)
            u64 wins[TOPK];
#pragma unroll
            for (int rd = 0; rd < TOPK; ++rd) {
                u64 wv = kk[0];
#pragma unroll
                for (int s2 = 1; s2 <= 32; s2 <<= 1) {
                    u64 o = __shfl_xor(wv, s2, 64);
                    if (o < wv) wv = o;
                }
                wins[rd] = wv;
                if (kk[0] == wv) {
#pragma unroll
                    for (int q = 0; q < TOPK - 1; ++q) kk[q] = kk[q + 1];
                    kk[TOPK - 1] = ~0ULL;
                }
            }

            // ---- epilogue (verbatim arithmetic from the exact-passing version)
            if (lane == 0) {
                const float area_g = (gx1 - gx0) * (gy1 - gy0);
                float vals[TOPK];
                float sum = 0.f;
#pragma unroll
                for (int r = 0; r < TOPK; ++r) {
                    int idx = (int)(u32)(wins[r] & 0xffffffffULL);
                    float4 a = a4[idx];
                    float area_a = (a.z - a.x) * (a.w - a.y);
                    float ltx = fmaxf(a.x, gx0), lty = fmaxf(a.y, gy0);
                    float rbx = fminf(a.z, gx1), rby = fminf(a.w, gy1);
                    float w2 = fmaxf(rbx - ltx, 0.f);
                    float h2 = fmaxf(rby - lty, 0.f);
                    float inter = w2 * h2;
                    float uni = area_a + area_g - inter;
                    float iou = inter / fmaxf(uni, 1e-12f);
                    vals[r] = iou;
                    sum += iou;
                }
                float mean = sum / 9.0f;
                float var = 0.f;
#pragma unroll
                for (int r = 0; r < TOPK; ++r) {
                    float d2 = vals[r] - mean;
                    var += d2 * d2;
                }
                float sd = sqrtf(var / 8.0f);   // ddof = 1
                thresh[m] = mean + sd;
            }
        }
    }

    grid.sync();

    // ================= phase 3: per-anchor assign ===========================
    for (int n = gtid; n < N; n += gstride) {
        float4 a = a4[n];
        float area_a = (a.z - a.x) * (a.w - a.y);
        float cx = (a.x + a.z) * 0.5f;
        float cy = (a.y + a.w) * 0.5f;

        int ig = min(GG - 1, max(0, (int)(cx * (1.0f / CELL_G))));
        int jg = min(GG - 1, max(0, (int)(cy * (1.0f / CELL_G))));
        int cell = jg * GG + ig;

        u64 best = 0;   // ((m+1) << 32) | f32_bits(iou); 0 = unmatched
        u32 cnt = min(cursG[cell], (u32)CAPG);
        u32 base = (u32)cell * CAPG;
        for (u32 t2 = 0; t2 < cnt; ++t2) {
            int mi = (int)gtBkt[base + t2];
            float4 g = g4[mi];
            if (cx >= g.x && cx <= g.z && cy >= g.y && cy <= g.w) {
                float area_g = (g.z - g.x) * (g.w - g.y);
                float ltx = fmaxf(a.x, g.x), lty = fmaxf(a.y, g.y);
                float rbx = fminf(a.z, g.z), rby = fminf(a.w, g.w);
                float ww = fmaxf(rbx - ltx, 0.f);
                float hh = fmaxf(rby - lty, 0.f);
                float inter = ww * hh;
                float uni = area_a + area_g - inter;
                float iou = inter / fmaxf(uni, 1e-12f);
                if (iou >= thresh[mi]) {
                    u64 cand = ((u64)(u32)(mi + 1) << 32) | __float_as_uint(iou);
                    if (cand > best) best = cand;
                }
            }
        }
        {   // overflow GTs (exactness net; 0 on this data)
            u32 nog = min(ovfCnt[1], (u32)OVG);
            for (u32 t2 = 0; t2 < nog; ++t2) {
                int mi = (int)ovGidx[t2];
                float4 g = g4[mi];
                if (cx >= g.x && cx <= g.z && cy >= g.y && cy <= g.w) {
                    float area_g = (g.z - g.x) * (g.w - g.y);
                    float ltx = fmaxf(a.x, g.x), lty = fmaxf(a.y, g.y);
                    float rbx = fminf(a.z, g.z), rby = fminf(a.w, g.w);
                    float ww = fmaxf(rbx - ltx, 0.f);
                    float hh = fmaxf(rby - lty, 0.f);
                    float inter = ww * hh;
                    float uni = area_a + area_g - inter;
                    float iou = inter / fmaxf(uni, 1e-12f);
                    if (iou >= thresh[mi]) {
                        u64 cand = ((u64)(u32)(mi + 1) << 32) | __float_as_uint(iou);
                        if (cand > best) best = cand;
                    }
                }
            }
        }

        int mm = (int)(best >> 32) - 1;
        out_idx[n] = (float)mm;
        out_iou[n] = (mm >= 0) ? __uint_as_float((u32)best) : 0.f;
    }
}

// ===========================================================================
// Fallback path (round-2, known-pass; needs only M floats of workspace)
// ===========================================================================
__global__ __launch_bounds__(256) void fb_centers(
    const float4* __restrict__ a4, float2* __restrict__ c2, int N)
{
    int n = blockIdx.x * 256 + threadIdx.x;
    if (n < N) {
        float4 a = a4[n];
        c2[n] = make_float2((a.x + a.z) * 0.5f, (a.y + a.w) * 0.5f);
    }
}

__global__ __launch_bounds__(256) void fb_thresh(
    const float4* __restrict__ a4, const float2* __restrict__ c2,
    const float* __restrict__ gts, float* __restrict__ thresh, int N)
{
    const int m = blockIdx.x;
    const int tid = threadIdx.x;
    const float gx0 = gts[m * 4 + 0], gy0 = gts[m * 4 + 1];
    const float gx1 = gts[m * 4 + 2], gy1 = gts[m * 4 + 3];
    const float gcx = (gx0 + gx1) * 0.5f;
    const float gcy = (gy0 + gy1) * 0.5f;

    float vmin = __builtin_inff();
    for (int n = tid; n < N; n += 512) {
        float2 c = c2[n];
        float dx = c.x - gcx, dy = c.y - gcy;
        vmin = fminf(vmin, dx * dx + dy * dy);
    }
    float v = vmin, w = 0.f;
#pragma unroll
    for (int r = 0; r < TOPK; ++r) {
        float t = v;
#pragma unroll
        for (int s = 1; s <= 32; s <<= 1) t = fminf(t, __shfl_xor(t, s, 64));
        w = t;
        if (v == w) v = __builtin_inff();
    }
    const float T = sqrtf(w) * 1.0001f + 1e-6f;

    u64 k[TOPK];
#pragma unroll
    for (int i = 0; i < TOPK; ++i) k[i] = ~0ULL;
    for (int n = tid; n < N; n += 256) {
        float2 c = c2[n];
        float dx = c.x - gcx, dy = c.y - gcy;
        float d = sqrtf(dx * dx + dy * dy);
        if (d <= T) {
            u64 key = ((u64)__float_as_uint(d) << 32) | (unsigned)n;
            if (key < k[TOPK - 1]) {
                u64 t = key;
#pragma unroll
                for (int i = 0; i < TOPK; ++i) {
                    u64 lo = (k[i] < t) ? k[i] : t;
                    u64 hi = (k[i] < t) ? t : k[i];
                    k[i] = lo;
                    t = hi;
                }
            }
        }
    }
    __shared__ u64 red[256];
    __shared__ int top9[TOPK];
#pragma unroll 1
    for (int r = 0; r < TOPK; ++r) {
        red[tid] = k[0];
        __syncthreads();
        for (int s = 128; s > 0; s >>= 1) {
            if (tid < s) {
                u64 o = red[tid + s];
                if (o < red[tid]) red[tid] = o;
            }
            __syncthreads();
        }
        u64 win = red[0];
        if (tid == 0) top9[r] = (int)(unsigned)(win & 0xffffffffULL);
        __syncthreads();
        if (k[0] == win) {
#pragma unroll
            for (int i = 0; i < TOPK - 1; ++i) k[i] = k[i + 1];
            k[TOPK - 1] = ~0ULL;
        }
    }
    if (tid == 0) {
        const float area_g = (gx1 - gx0) * (gy1 - gy0);
        float vals[TOPK];
        float s = 0.f;
#pragma unroll
        for (int r = 0; r < TOPK; ++r) {
            float4 a = a4[top9[r]];
            float area_a = (a.z - a.x) * (a.w - a.y);
            float ltx = fmaxf(a.x, gx0), lty = fmaxf(a.y, gy0);
            float rbx = fminf(a.z, gx1), rby = fminf(a.w, gy1);
            float w2 = fmaxf(rbx - ltx, 0.f);
            float h2 = fmaxf(rby - lty, 0.f);
            float inter = w2 * h2;
            float uni = area_a + area_g - inter;
            float iou = inter / fmaxf(uni, 1e-12f);
            vals[r] = iou;
            s += iou;
        }
        float mean = s / 9.0f;
        float var = 0.f;
#pragma unroll
        for (int r = 0; r < TOPK; ++r) {
            float d2 = vals[r] - mean;
            var += d2 * d2;
        }
        thresh[m] = mean + sqrtf(var / 8.0f);
    }
}

__global__ __launch_bounds__(256) void fb_assign(
    const float4* __restrict__ a4, const float4* __restrict__ g4,
    const float* __restrict__ thresh,
    float* __restrict__ out_idx, float* __restrict__ out_iou, int N, int M)
{
    extern __shared__ char smem[];
    float4* sg = (float4*)smem;
    float2* se = (float2*)(smem + (size_t)M * 16);
    for (int i = threadIdx.x; i < M; i += 256) {
        float4 g = g4[i];
        sg[i] = g;
        se[i] = make_float2((g.z - g.x) * (g.w - g.y), thresh[i]);
    }
    __syncthreads();
    int n = blockIdx.x * 256 + threadIdx.x;
    if (n >= N) return;
    float4 a = a4[n];
    float area_a = (a.z - a.x) * (a.w - a.y);
    float cx = (a.x + a.z) * 0.5f;
    float cy = (a.y + a.w) * 0.5f;
    u64 best = 0;
    for (int mi = 0; mi < M; ++mi) {
        float4 g = sg[mi];
        if (cx >= g.x && cx <= g.z && cy >= g.y && cy <= g.w) {
            float2 e = se[mi];
            float ltx = fmaxf(a.x, g.x), lty = fmaxf(a.y, g.y);
            float rbx = fminf(a.z, g.z), rby = fminf(a.w, g.w);
            float w = fmaxf(rbx - ltx, 0.f);
            float h = fmaxf(rby - lty, 0.f);
            float inter = w * h;
            float uni = area_a + e.x - inter;
            float iou = inter / fmaxf(uni, 1e-12f);
            if (iou >= e.y)
                best = ((u64)(u32)(mi + 1) << 32) | __float_as_uint(iou);
        }
    }
    int mm = (int)(best >> 32) - 1;
    out_idx[n] = (float)mm;
    out_iou[n] = (mm >= 0) ? __uint_as_float((u32)best) : 0.f;
}

// ===========================================================================
extern "C" void kernel_launch(void* const* d_in, const int* in_sizes, int n_in,
                              void* d_out, int out_size, void* d_ws, size_t ws_size,
                              hipStream_t stream) {
    const float4* a4 = (const float4*)d_in[0];
    const float4* g4 = (const float4*)d_in[1];
    const float* gts = (const float*)d_in[1];
    int N = in_sizes[0] / 4;   // 120000
    int M = in_sizes[1] / 4;   // 800

    // ws layout (u32 units); cursA/cursG/ovfCnt contiguous for one zero pass
    const size_t oCursA  = 0;                          // NCA
    const size_t oCursG  = oCursA + NCA;               // NCG
    const size_t oOvfCnt = oCursG + NCG;               // 2
    const size_t oThresh = oOvfCnt + 2;                // M
    size_t oBkCtr = oThresh + (size_t)M;
    oBkCtr = (oBkCtr + 1) & ~(size_t)1;                // 8B align for float2
    const size_t oBkIdx  = oBkCtr + 2 * (size_t)NCA * CAPA;
    const size_t oGtBkt  = oBkIdx + (size_t)NCA * CAPA;
    const size_t oOvAidx = oGtBkt + (size_t)NCG * CAPG;
    size_t oOvActr = oOvAidx + OVA;
    oOvActr = (oOvActr + 1) & ~(size_t)1;              // 8B align
    const size_t oOvGidx = oOvActr + 2 * (size_t)OVA;
    const size_t needBytes = (oOvGidx + OVG) * sizeof(u32);

    if (ws_size >= needBytes) {
        u32* w = (u32*)d_ws;
        float* outf = (float*)d_out;
        int nblk = (N + M + 255) / 256;                // covers insert + assign
        int qblk = (M + 3) / 4;                        // covers query waves
        if (qblk > nblk) nblk = qblk;
        // 472 blocks x 256 thr: co-resident even at 256 VGPR (>=2 blk/CU x 256 CU)
        void* args[] = { (void*)&a4, (void*)&g4, (void*)&w, (void*)&outf,
                         (void*)&N, (void*)&M };
        hipLaunchCooperativeKernel((const void*)atss_fused,
                                   dim3((unsigned)nblk), dim3(256),
                                   args, 0, stream);
    } else {
        // fallback: round-2 path
        float* thr = (float*)d_ws;
        float2* centers = (float2*)d_out;
        fb_centers<<<(N + 255) / 256, 256, 0, stream>>>(a4, centers, N);
        fb_thresh<<<M, 256, 0, stream>>>(a4, (const float2*)centers, gts, thr, N);
        size_t lds = (size_t)M * 24;
        fb_assign<<<(N + 255) / 256, 256, lds, stream>>>(
            a4, g4, thr, (float*)d_out, (float*)d_out + N, N, M);
    }
}

// Round 2
// 160.018 us; speedup vs baseline: 1.1996x; 1.1996x over previous
//
#include <hip/hip_runtime.h>
#include <stdint.h>

typedef unsigned int u32;
typedef unsigned long long u64;

#define TOPK 9
#define GA 64            // anchor grid: 64x64 cells of 16px
#define CELL_A 16.0f
#define NCA (GA * GA)    // 4096
#define GG 16            // GT grid: 16x16 cells of 64px
#define CELL_G 64.0f
#define NCG (GG * GG)    // 256
#define CAPA 96          // anchor bucket capacity (lambda~29, max~56 at N=120k)
#define CAPG 160         // GT bucket capacity (lambda~8)
#define OVA 8192         // anchor overflow list capacity (exactness net)
#define OVG 1024         // GT overflow list capacity

#define MAGA 0x5A17C3D9u // init-done magic pair (two DIFFERENT words: a constant
#define MAGB 0xA6E83C26u // or byte-pattern poison fill cannot match both)

// Lightweight full-grid barrier: 1 atomic arrival per block + spin with
// s_sleep backoff. __threadfence() (agent scope) on both sides provides the
// cross-XCD L2 writeback / invalidate that correctness requires.
__device__ __forceinline__ void gbarrier(u32* cnt, u32 nblk)
{
    __syncthreads();
    if (threadIdx.x == 0) {
        __threadfence();   // release: all this block's stores -> coherence point
        __hip_atomic_fetch_add(cnt, 1u, __ATOMIC_RELAXED, __HIP_MEMORY_SCOPE_AGENT);
        while (__hip_atomic_load(cnt, __ATOMIC_RELAXED, __HIP_MEMORY_SCOPE_AGENT) < nblk)
            __builtin_amdgcn_s_sleep(4);
        __threadfence();   // acquire: drop stale L1/L2 lines before reading
    }
    __syncthreads();
}

// ===========================================================================
// Single cooperative kernel: init -> insert -> query -> assign with custom
// barriers (cg::grid.sync measured ~55us each on this chip -- replaced).
// Phase bodies verbatim from the 4-dispatch absmax-0 version.
// ===========================================================================
__global__ __launch_bounds__(256) void atss_fused(
    const float4* __restrict__ a4, const float4* __restrict__ g4,
    u32* __restrict__ w, float* __restrict__ outp, int N, int M)
{
    // ---- workspace layout (mirrors kernel_launch) ----
    const size_t oCursA  = 0;
    const size_t oCursG  = oCursA + NCA;
    const size_t oOvfCnt = oCursG + NCG;
    const size_t oThresh = oOvfCnt + 2;
    size_t oBkCtr = oThresh + (size_t)M;
    oBkCtr = (oBkCtr + 1) & ~(size_t)1;                // 8B align for float2
    const size_t oBkIdx  = oBkCtr + 2 * (size_t)NCA * CAPA;
    const size_t oGtBkt  = oBkIdx + (size_t)NCA * CAPA;
    const size_t oOvAidx = oGtBkt + (size_t)NCG * CAPG;
    size_t oOvActr = oOvAidx + OVA;
    oOvActr = (oOvActr + 1) & ~(size_t)1;              // 8B align
    const size_t oOvGidx = oOvActr + 2 * (size_t)OVA;
    const size_t oCtrl   = oOvGidx + OVG;              // [0,1]=magic [2]=cnt1 [3]=cnt2

    u32* cursA     = w + oCursA;
    u32* cursG     = w + oCursG;
    u32* ovfCnt    = w + oOvfCnt;
    float* thresh  = (float*)(w + oThresh);
    float2* bkCtr  = (float2*)(w + oBkCtr);
    u32* bkIdx     = w + oBkIdx;
    u32* gtBkt     = w + oGtBkt;
    u32* ovAidx    = w + oOvAidx;
    float2* ovActr = (float2*)(w + oOvActr);
    u32* ovGidx    = w + oOvGidx;
    u32* ctrl      = w + oCtrl;
    const float* gts = (const float*)g4;
    float* out_idx = outp;
    float* out_iou = outp + N;

    const int tid  = (int)threadIdx.x;
    const int bid  = (int)blockIdx.x;
    const u32 nblk = gridDim.x;
    const int gtid = bid * 256 + tid;
    const int gstride = (int)nblk * 256;

    // ================= phase 0: init (block 0 zeroes, broadcasts magic) ====
    if (bid == 0) {
        for (int i = tid; i < NCA + NCG + 2; i += 256) w[i] = 0u;
        if (tid < 2) ctrl[2 + tid] = 0u;               // barrier counters
        __syncthreads();
        if (tid == 0) {
            __threadfence();                           // zeros -> visible
            __hip_atomic_store(&ctrl[0], MAGA, __ATOMIC_RELAXED, __HIP_MEMORY_SCOPE_AGENT);
            __hip_atomic_store(&ctrl[1], MAGB, __ATOMIC_RELAXED, __HIP_MEMORY_SCOPE_AGENT);
        }
    } else {
        if (tid == 0) {
            while (!(__hip_atomic_load(&ctrl[0], __ATOMIC_RELAXED, __HIP_MEMORY_SCOPE_AGENT) == MAGA &&
                     __hip_atomic_load(&ctrl[1], __ATOMIC_RELAXED, __HIP_MEMORY_SCOPE_AGENT) == MAGB))
                __builtin_amdgcn_s_sleep(4);
            __threadfence();                           // acquire zeros
        }
        __syncthreads();
    }

    // ================= phase 1: direct bucket insert ========================
    for (int gid = gtid; gid < N + M; gid += gstride) {
        if (gid < N) {
            float4 a = a4[gid];
            float cx = (a.x + a.z) * 0.5f;
            float cy = (a.y + a.w) * 0.5f;
            int ix = min(GA - 1, max(0, (int)(cx * (1.0f / CELL_A))));
            int iy = min(GA - 1, max(0, (int)(cy * (1.0f / CELL_A))));
            int cell = iy * GA + ix;
            u32 p = atomicAdd(&cursA[cell], 1u);
            if (p < CAPA) {
                bkCtr[cell * CAPA + p] = make_float2(cx, cy);
                bkIdx[cell * CAPA + p] = (u32)gid;
            } else {
                u32 q = atomicAdd(&ovfCnt[0], 1u);
                if (q < OVA) { ovAidx[q] = (u32)gid; ovActr[q] = make_float2(cx, cy); }
            }
        } else {
            int m = gid - N;
            float4 g = g4[m];
            int ix0 = min(GG - 1, max(0, (int)floorf(g.x * (1.0f / CELL_G))));
            int iy0 = min(GG - 1, max(0, (int)floorf(g.y * (1.0f / CELL_G))));
            int ix1 = min(GG - 1, max(0, (int)floorf(g.z * (1.0f / CELL_G))));
            int iy1 = min(GG - 1, max(0, (int)floorf(g.w * (1.0f / CELL_G))));
            for (int j = iy0; j <= iy1; ++j)
                for (int i = ix0; i <= ix1; ++i) {
                    int cell = j * GG + i;
                    u32 p = atomicAdd(&cursG[cell], 1u);
                    if (p < CAPG) gtBkt[cell * CAPG + p] = (u32)m;
                    else {
                        u32 q = atomicAdd(&ovfCnt[1], 1u);
                        if (q < OVG) ovGidx[q] = (u32)m;
                    }
                }
        }
    }

    gbarrier(&ctrl[2], nblk);
    // magics no longer needed this launch; clear them so the init wait is
    // correct even if the harness does NOT re-poison before the next replay.
    if (bid == 0 && tid == 0) {
        __hip_atomic_store(&ctrl[0], 0u, __ATOMIC_RELAXED, __HIP_MEMORY_SCOPE_AGENT);
        __hip_atomic_store(&ctrl[1], 0u, __ATOMIC_RELAXED, __HIP_MEMORY_SCOPE_AGENT);
    }

    // ================= phase 2: per-GT query (one wave per GT) ==============
    {
        const int lane = tid & 63;
        for (int m = (gtid >> 6); m < M; m += (gstride >> 6)) {
            const float gx0 = gts[m * 4 + 0], gy0 = gts[m * 4 + 1];
            const float gx1 = gts[m * 4 + 2], gy1 = gts[m * 4 + 3];
            const float gcx = (gx0 + gx1) * 0.5f;
            const float gcy = (gy0 + gy1) * 0.5f;
            const int ci = min(GA - 1, max(0, (int)(gcx * (1.0f / CELL_A))));
            const int cj = min(GA - 1, max(0, (int)(gcy * (1.0f / CELL_A))));

            // ---- stage 1: expand Chebyshev rings until >=9 anchors counted.
            u32 cum = 0;
            float maxd2 = 0.f;
            for (int r = 0; r < GA && cum < TOPK; ++r) {
                int ncell = (r == 0) ? 1 : 8 * r;
                u32 myc = 0;
                float mymax = 0.f;
                for (int k = lane; k < ncell; k += 64) {
                    int di = 0, dj = 0;
                    if (r > 0) {
                        int side = k / (2 * r), pos = k % (2 * r);
                        if (side == 0)      { di = -r + pos; dj = -r; }
                        else if (side == 1) { di = r;        dj = -r + pos; }
                        else if (side == 2) { di = r - pos;  dj = r; }
                        else                { di = -r;       dj = r - pos; }
                    }
                    int i = ci + di, j = cj + dj;
                    if (i < 0 || i >= GA || j < 0 || j >= GA) continue;
                    u32 cnt = cursA[j * GA + i];
                    if (cnt) {
                        myc += cnt;
                        float x0 = i * CELL_A, x1 = x0 + CELL_A;
                        float y0 = j * CELL_A, y1 = y0 + CELL_A;
                        float dxm = fmaxf(gcx - x0, x1 - gcx);
                        float dym = fmaxf(gcy - y0, y1 - gcy);
                        mymax = fmaxf(mymax, dxm * dxm + dym * dym);
                    }
                }
#pragma unroll
                for (int s2 = 1; s2 <= 32; s2 <<= 1) {
                    myc += __shfl_xor(myc, s2, 64);
                    mymax = fmaxf(mymax, __shfl_xor(mymax, s2, 64));
                }
                cum += myc;
                maxd2 = fmaxf(maxd2, mymax);
            }
            const float D2pad = maxd2 * 1.0001f + 1.0f;  // absorbs fp rounding + sqrt ties

            // ---- stage 2: exact top-9 over bucket slots (+ overflow).
            u64 kk[TOPK];
#pragma unroll
            for (int i = 0; i < TOPK; ++i) kk[i] = ~0ULL;

            const int rs = 1 + (int)(sqrtf(D2pad) * (1.0f / CELL_A));
            const int jlo = max(0, cj - rs), jhi = min(GA - 1, cj + rs);
            const int ilo = max(0, ci - rs), ihi = min(GA - 1, ci + rs);
            for (int j = jlo; j <= jhi; ++j) {
                float y0 = j * CELL_A, y1 = y0 + CELL_A;
                float mdy = fmaxf(fmaxf(y0 - gcy, gcy - y1), 0.f);
                for (int i = ilo; i <= ihi; ++i) {
                    float x0 = i * CELL_A, x1 = x0 + CELL_A;
                    float mdx = fmaxf(fmaxf(x0 - gcx, gcx - x1), 0.f);
                    if (mdx * mdx + mdy * mdy > D2pad) continue;
                    int c = j * GA + i;
                    u32 cnt = min(cursA[c], (u32)CAPA);
                    u32 base = (u32)c * CAPA;
                    for (u32 tc = lane; tc < cnt; tc += 64) {
                        u32 n = bkIdx[base + tc];
                        float2 cc = bkCtr[base + tc];
                        float ddx = cc.x - gcx, ddy = cc.y - gcy;
                        float d2 = ddx * ddx + ddy * ddy;
                        if (d2 <= D2pad) {
                            float d = sqrtf(d2);
                            u64 key = ((u64)__float_as_uint(d) << 32) | n;
                            if (key < kk[TOPK - 1]) {
                                u64 t2 = key;
#pragma unroll
                                for (int q = 0; q < TOPK; ++q) {
                                    u64 lo = (kk[q] < t2) ? kk[q] : t2;
                                    u64 hi = (kk[q] < t2) ? t2 : kk[q];
                                    kk[q] = lo;
                                    t2 = hi;
                                }
                            }
                        }
                    }
                }
            }
            {   // overflow anchors (exactness net; count is 0 on this data)
                u32 nov = min(ovfCnt[0], (u32)OVA);
                for (u32 tc = lane; tc < nov; tc += 64) {
                    u32 n = ovAidx[tc];
                    float2 cc = ovActr[tc];
                    float ddx = cc.x - gcx, ddy = cc.y - gcy;
                    float d2 = ddx * ddx + ddy * ddy;
                    if (d2 <= D2pad) {
                        float d = sqrtf(d2);
                        u64 key = ((u64)__float_as_uint(d) << 32) | n;
                        if (key < kk[TOPK - 1]) {
                            u64 t2 = key;
#pragma unroll
                            for (int q = 0; q < TOPK; ++q) {
                                u64 lo = (kk[q] < t2) ? kk[q] : t2;
                                u64 hi = (kk[q] < t2) ? t2 : kk[q];
                                kk[q] = lo;
                                t2 = hi;
                            }
                        }
                    }
                }
            }

            // ---- wave merge: 9 pop-min rounds (u64 butterfly)
            u64 wins[TOPK];
#pragma unroll
            for (int rd = 0; rd < TOPK; ++rd) {
                u64 wv = kk[0];
#pragma unroll
                for (int s2 = 1; s2 <= 32; s2 <<= 1) {
                    u64 o = __shfl_xor(wv, s2, 64);
                    if (o < wv) wv = o;
                }
                wins[rd] = wv;
                if (kk[0] == wv) {
#pragma unroll
                    for (int q = 0; q < TOPK - 1; ++q) kk[q] = kk[q + 1];
                    kk[TOPK - 1] = ~0ULL;
                }
            }

            // ---- epilogue (verbatim arithmetic from the exact-passing version)
            if (lane == 0) {
                const float area_g = (gx1 - gx0) * (gy1 - gy0);
                float vals[TOPK];
                float sum = 0.f;
#pragma unroll
                for (int r = 0; r < TOPK; ++r) {
                    int idx = (int)(u32)(wins[r] & 0xffffffffULL);
                    float4 a = a4[idx];
                    float area_a = (a.z - a.x) * (a.w - a.y);
                    float ltx = fmaxf(a.x, gx0), lty = fmaxf(a.y, gy0);
                    float rbx = fminf(a.z, gx1), rby = fminf(a.w, gy1);
                    float w2 = fmaxf(rbx - ltx, 0.f);
                    float h2 = fmaxf(rby - lty, 0.f);
                    float inter = w2 * h2;
                    float uni = area_a + area_g - inter;
                    float iou = inter / fmaxf(uni, 1e-12f);
                    vals[r] = iou;
                    sum += iou;
                }
                float mean = sum / 9.0f;
                float var = 0.f;
#pragma unroll
                for (int r = 0; r < TOPK; ++r) {
                    float d2 = vals[r] - mean;
                    var += d2 * d2;
                }
                float sd = sqrtf(var / 8.0f);   // ddof = 1
                thresh[m] = mean + sd;
            }
        }
    }

    gbarrier(&ctrl[3], nblk);

    // ================= phase 3: per-anchor assign ===========================
    for (int n = gtid; n < N; n += gstride) {
        float4 a = a4[n];
        float area_a = (a.z - a.x) * (a.w - a.y);
        float cx = (a.x + a.z) * 0.5f;
        float cy = (a.y + a.w) * 0.5f;

        int ig = min(GG - 1, max(0, (int)(cx * (1.0f / CELL_G))));
        int jg = min(GG - 1, max(0, (int)(cy * (1.0f / CELL_G))));
        int cell = jg * GG + ig;

        u64 best = 0;   // ((m+1) << 32) | f32_bits(iou); 0 = unmatched
        u32 cnt = min(cursG[cell], (u32)CAPG);
        u32 base = (u32)cell * CAPG;
        for (u32 t2 = 0; t2 < cnt; ++t2) {
            int mi = (int)gtBkt[base + t2];
            float4 g = g4[mi];
            if (cx >= g.x && cx <= g.z && cy >= g.y && cy <= g.w) {
                float area_g = (g.z - g.x) * (g.w - g.y);
                float ltx = fmaxf(a.x, g.x), lty = fmaxf(a.y, g.y);
                float rbx = fminf(a.z, g.z), rby = fminf(a.w, g.w);
                float ww = fmaxf(rbx - ltx, 0.f);
                float hh = fmaxf(rby - lty, 0.f);
                float inter = ww * hh;
                float uni = area_a + area_g - inter;
                float iou = inter / fmaxf(uni, 1e-12f);
                if (iou >= thresh[mi]) {
                    u64 cand = ((u64)(u32)(mi + 1) << 32) | __float_as_uint(iou);
                    if (cand > best) best = cand;
                }
            }
        }
        {   // overflow GTs (exactness net; 0 on this data)
            u32 nog = min(ovfCnt[1], (u32)OVG);
            for (u32 t2 = 0; t2 < nog; ++t2) {
                int mi = (int)ovGidx[t2];
                float4 g = g4[mi];
                if (cx >= g.x && cx <= g.z && cy >= g.y && cy <= g.w) {
                    float area_g = (g.z - g.x) * (g.w - g.y);
                    float ltx = fmaxf(a.x, g.x), lty = fmaxf(a.y, g.y);
                    float rbx = fminf(a.z, g.z), rby = fminf(a.w, g.w);
                    float ww = fmaxf(rbx - ltx, 0.f);
                    float hh = fmaxf(rby - lty, 0.f);
                    float inter = ww * hh;
                    float uni = area_a + area_g - inter;
                    float iou = inter / fmaxf(uni, 1e-12f);
                    if (iou >= thresh[mi]) {
                        u64 cand = ((u64)(u32)(mi + 1) << 32) | __float_as_uint(iou);
                        if (cand > best) best = cand;
                    }
                }
            }
        }

        int mm = (int)(best >> 32) - 1;
        out_idx[n] = (float)mm;
        out_iou[n] = (mm >= 0) ? __uint_as_float((u32)best) : 0.f;
    }
}

// ===========================================================================
// Fallback path (round-2, known-pass; needs only M floats of workspace)
// ===========================================================================
__global__ __launch_bounds__(256) void fb_centers(
    const float4* __restrict__ a4, float2* __restrict__ c2, int N)
{
    int n = blockIdx.x * 256 + threadIdx.x;
    if (n < N) {
        float4 a = a4[n];
        c2[n] = make_float2((a.x + a.z) * 0.5f, (a.y + a.w) * 0.5f);
    }
}

__global__ __launch_bounds__(256) void fb_thresh(
    const float4* __restrict__ a4, const float2* __restrict__ c2,
    const float* __restrict__ gts, float* __restrict__ thresh, int N)
{
    const int m = blockIdx.x;
    const int tid = threadIdx.x;
    const float gx0 = gts[m * 4 + 0], gy0 = gts[m * 4 + 1];
    const float gx1 = gts[m * 4 + 2], gy1 = gts[m * 4 + 3];
    const float gcx = (gx0 + gx1) * 0.5f;
    const float gcy = (gy0 + gy1) * 0.5f;

    float vmin = __builtin_inff();
    for (int n = tid; n < N; n += 512) {
        float2 c = c2[n];
        float dx = c.x - gcx, dy = c.y - gcy;
        vmin = fminf(vmin, dx * dx + dy * dy);
    }
    float v = vmin, w = 0.f;
#pragma unroll
    for (int r = 0; r < TOPK; ++r) {
        float t = v;
#pragma unroll
        for (int s = 1; s <= 32; s <<= 1) t = fminf(t, __shfl_xor(t, s, 64));
        w = t;
        if (v == w) v = __builtin_inff();
    }
    const float T = sqrtf(w) * 1.0001f + 1e-6f;

    u64 k[TOPK];
#pragma unroll
    for (int i = 0; i < TOPK; ++i) k[i] = ~0ULL;
    for (int n = tid; n < N; n += 256) {
        float2 c = c2[n];
        float dx = c.x - gcx, dy = c.y - gcy;
        float d = sqrtf(dx * dx + dy * dy);
        if (d <= T) {
            u64 key = ((u64)__float_as_uint(d) << 32) | (unsigned)n;
            if (key < k[TOPK - 1]) {
                u64 t = key;
#pragma unroll
                for (int i = 0; i < TOPK; ++i) {
                    u64 lo = (k[i] < t) ? k[i] : t;
                    u64 hi = (k[i] < t) ? t : k[i];
                    k[i] = lo;
                    t = hi;
                }
            }
        }
    }
    __shared__ u64 red[256];
    __shared__ int top9[TOPK];
#pragma unroll 1
    for (int r = 0; r < TOPK; ++r) {
        red[tid] = k[0];
        __syncthreads();
        for (int s = 128; s > 0; s >>= 1) {
            if (tid < s) {
                u64 o = red[tid + s];
                if (o < red[tid]) red[tid] = o;
            }
            __syncthreads();
        }
        u64 win = red[0];
        if (tid == 0) top9[r] = (int)(unsigned)(win & 0xffffffffULL);
        __syncthreads();
        if (k[0] == win) {
#pragma unroll
            for (int i = 0; i < TOPK - 1; ++i) k[i] = k[i + 1];
            k[TOPK - 1] = ~0ULL;
        }
    }
    if (tid == 0) {
        const float area_g = (gx1 - gx0) * (gy1 - gy0);
        float vals[TOPK];
        float s = 0.f;
#pragma unroll
        for (int r = 0; r < TOPK; ++r) {
            float4 a = a4[top9[r]];
            float area_a = (a.z - a.x) * (a.w - a.y);
            float ltx = fmaxf(a.x, gx0), lty = fmaxf(a.y, gy0);
            float rbx = fminf(a.z, gx1), rby = fminf(a.w, gy1);
            float w2 = fmaxf(rbx - ltx, 0.f);
            float h2 = fmaxf(rby - lty, 0.f);
            float inter = w2 * h2;
            float uni = area_a + area_g - inter;
            float iou = inter / fmaxf(uni, 1e-12f);
            vals[r] = iou;
            s += iou;
        }
        float mean = s / 9.0f;
        float var = 0.f;
#pragma unroll
        for (int r = 0; r < TOPK; ++r) {
            float d2 = vals[r] - mean;
            var += d2 * d2;
        }
        thresh[m] = mean + sqrtf(var / 8.0f);
    }
}

__global__ __launch_bounds__(256) void fb_assign(
    const float4* __restrict__ a4, const float4* __restrict__ g4,
    const float* __restrict__ thresh,
    float* __restrict__ out_idx, float* __restrict__ out_iou, int N, int M)
{
    extern __shared__ char smem[];
    float4* sg = (float4*)smem;
    float2* se = (float2*)(smem + (size_t)M * 16);
    for (int i = threadIdx.x; i < M; i += 256) {
        float4 g = g4[i];
        sg[i] = g;
        se[i] = make_float2((g.z - g.x) * (g.w - g.y), thresh[i]);
    }
    __syncthreads();
    int n = blockIdx.x * 256 + threadIdx.x;
    if (n >= N) return;
    float4 a = a4[n];
    float area_a = (a.z - a.x) * (a.w - a.y);
    float cx = (a.x + a.z) * 0.5f;
    float cy = (a.y + a.w) * 0.5f;
    u64 best = 0;
    for (int mi = 0; mi < M; ++mi) {
        float4 g = sg[mi];
        if (cx >= g.x && cx <= g.z && cy >= g.y && cy <= g.w) {
            float2 e = se[mi];
            float ltx = fmaxf(a.x, g.x), lty = fmaxf(a.y, g.y);
            float rbx = fminf(a.z, g.z), rby = fminf(a.w, g.w);
            float w = fmaxf(rbx - ltx, 0.f);
            float h = fmaxf(rby - lty, 0.f);
            float inter = w * h;
            float uni = area_a + e.x - inter;
            float iou = inter / fmaxf(uni, 1e-12f);
            if (iou >= e.y)
                best = ((u64)(u32)(mi + 1) << 32) | __float_as_uint(iou);
        }
    }
    int mm = (int)(best >> 32) - 1;
    out_idx[n] = (float)mm;
    out_iou[n] = (mm >= 0) ? __uint_as_float((u32)best) : 0.f;
}

// ===========================================================================
extern "C" void kernel_launch(void* const* d_in, const int* in_sizes, int n_in,
                              void* d_out, int out_size, void* d_ws, size_t ws_size,
                              hipStream_t stream) {
    const float4* a4 = (const float4*)d_in[0];
    const float4* g4 = (const float4*)d_in[1];
    const float* gts = (const float*)d_in[1];
    int N = in_sizes[0] / 4;   // 120000
    int M = in_sizes[1] / 4;   // 800

    // ws layout (u32 units)
    const size_t oCursA  = 0;                          // NCA
    const size_t oCursG  = oCursA + NCA;               // NCG
    const size_t oOvfCnt = oCursG + NCG;               // 2
    const size_t oThresh = oOvfCnt + 2;                // M
    size_t oBkCtr = oThresh + (size_t)M;
    oBkCtr = (oBkCtr + 1) & ~(size_t)1;                // 8B align for float2
    const size_t oBkIdx  = oBkCtr + 2 * (size_t)NCA * CAPA;
    const size_t oGtBkt  = oBkIdx + (size_t)NCA * CAPA;
    const size_t oOvAidx = oGtBkt + (size_t)NCG * CAPG;
    size_t oOvActr = oOvAidx + OVA;
    oOvActr = (oOvActr + 1) & ~(size_t)1;              // 8B align
    const size_t oOvGidx = oOvActr + 2 * (size_t)OVA;
    const size_t oCtrl   = oOvGidx + OVG;              // 4 control words
    const size_t needBytes = (oCtrl + 4) * sizeof(u32);

    bool launched = false;
    if (ws_size >= needBytes) {
        u32* w = (u32*)d_ws;
        float* outf = (float*)d_out;
        int nblk = (N + M + 255) / 256;                // covers insert phase
        int qblk = (M + 3) / 4;
        if (qblk > nblk) nblk = qblk;
        // 472 blocks x 256 thr @ ~56 VGPR: far below co-residency capacity;
        // cooperative launch makes the guarantee hard.
        void* args[] = { (void*)&a4, (void*)&g4, (void*)&w, (void*)&outf,
                         (void*)&N, (void*)&M };
        hipError_t e = hipLaunchCooperativeKernel((const void*)atss_fused,
                                                  dim3((unsigned)nblk), dim3(256),
                                                  args, 0, stream);
        launched = (e == hipSuccess);
    }
    if (!launched) {
        // fallback: round-2 path (also used if cooperative launch refused)
        float* thr = (float*)d_ws;
        float2* centers = (float2*)d_out;
        fb_centers<<<(N + 255) / 256, 256, 0, stream>>>(a4, centers, N);
        fb_thresh<<<M, 256, 0, stream>>>(a4, (const float2*)centers, gts, thr, N);
        size_t lds = (size_t)M * 24;
        fb_assign<<<(N + 255) / 256, 256, lds, stream>>>(
            a4, g4, thr, (float*)d_out, (float*)d_out + N, N, M);
    }
}

// Round 3
// 49.706 us; speedup vs baseline: 3.8619x; 3.2193x over previous
//
#include <hip/hip_runtime.h>
#include <stdint.h>

typedef unsigned int u32;
typedef unsigned long long u64;

#define TOPK 9
#define GA 64            // anchor grid: 64x64 cells of 16px
#define CELL_A 16.0f
#define NCA (GA * GA)    // 4096
#define GG 16            // GT grid: 16x16 cells of 64px
#define CELL_G 64.0f
#define NCG (GG * GG)    // 256
#define CAPA 96          // anchor bucket capacity (max ~56 at N=120k)
#define CAPG 160         // GT bucket capacity (lambda~8)
#define OVA 8192         // anchor overflow list capacity (exactness net)
#define OVG 1024         // GT overflow list capacity

// ===========================================================================
// Dispatch 1: zero cursors + overflow counters (4354 contiguous words).
// ===========================================================================
__global__ __launch_bounds__(256) void zero_counts(u32* __restrict__ p, int n)
{
    int i = blockIdx.x * 256 + threadIdx.x;
    if (i < n) p[i] = 0u;
}

// ===========================================================================
// Dispatch 2: direct bucket insert.
// Anchors -> packed 16B slots {cx, cy, idx_bits, 0} (ONE dwordx4 store).
// GTs -> per-cell box copies (float4) + index list.
// Overflow lists keep this exact for ANY input distribution.
// ===========================================================================
__global__ __launch_bounds__(256) void bucket_insert(
    const float4* __restrict__ a4, const float4* __restrict__ g4,
    u32* __restrict__ cursA, u32* __restrict__ cursG, u32* __restrict__ ovfCnt,
    float4* __restrict__ slotA, float4* __restrict__ gtBox,
    u32* __restrict__ gtBkt,
    u32* __restrict__ ovAidx, float2* __restrict__ ovActr,
    u32* __restrict__ ovGidx, int N, int M)
{
    int gid = blockIdx.x * 256 + threadIdx.x;
    if (gid < N) {
        float4 a = a4[gid];
        float cx = (a.x + a.z) * 0.5f;
        float cy = (a.y + a.w) * 0.5f;
        int ix = min(GA - 1, max(0, (int)(cx * (1.0f / CELL_A))));
        int iy = min(GA - 1, max(0, (int)(cy * (1.0f / CELL_A))));
        int cell = iy * GA + ix;
        u32 p = atomicAdd(&cursA[cell], 1u);
        if (p < CAPA) {
            slotA[cell * CAPA + p] =
                make_float4(cx, cy, __uint_as_float((u32)gid), 0.f);
        } else {
            u32 q = atomicAdd(&ovfCnt[0], 1u);
            if (q < OVA) { ovAidx[q] = (u32)gid; ovActr[q] = make_float2(cx, cy); }
        }
    } else if (gid < N + M) {
        int m = gid - N;
        float4 g = g4[m];
        int ix0 = min(GG - 1, max(0, (int)floorf(g.x * (1.0f / CELL_G))));
        int iy0 = min(GG - 1, max(0, (int)floorf(g.y * (1.0f / CELL_G))));
        int ix1 = min(GG - 1, max(0, (int)floorf(g.z * (1.0f / CELL_G))));
        int iy1 = min(GG - 1, max(0, (int)floorf(g.w * (1.0f / CELL_G))));
        for (int j = iy0; j <= iy1; ++j)
            for (int i = ix0; i <= ix1; ++i) {
                int cell = j * GG + i;
                u32 p = atomicAdd(&cursG[cell], 1u);
                if (p < CAPG) {
                    gtBox[cell * CAPG + p] = g;
                    gtBkt[cell * CAPG + p] = (u32)m;
                } else {
                    u32 q = atomicAdd(&ovfCnt[1], 1u);
                    if (q < OVG) ovGidx[q] = (u32)m;
                }
            }
    }
}

// ===========================================================================
// Dispatch 3: query. ONE BLOCK (4 waves / 256 lanes) per GT.
//  - stage 1: rings 0..3 counted in parallel (one ring per wave), LDS
//    exchange; prefix over rings reproduces the serial ring-walk semantics
//    bitwise. (Serial fallback continues rings 4.. in the cum<9 case.)
//  - stage 2: cell scan strided across 4 waves, slots strided across lanes,
//    per-lane exact top-9 by u64 keys; per-wave butterfly pop-min, then a
//    36-entry cross-wave merge. Key set identical to the 1-wave version
//    (unique u64 keys), so thresh arithmetic is verbatim-identical.
// ===========================================================================
__global__ __launch_bounds__(256) void atss_query(
    const float4* __restrict__ a4, const float* __restrict__ gts,
    const u32* __restrict__ cursA, const float4* __restrict__ slotA,
    const u32* __restrict__ ovfCnt,
    const u32* __restrict__ ovAidx, const float2* __restrict__ ovActr,
    float* __restrict__ thresh, int M)
{
    const int m = blockIdx.x;
    if (m >= M) return;
    const int tid  = (int)threadIdx.x;
    const int wid  = tid >> 6;
    const int lane = tid & 63;

    __shared__ u32   s_cnt[4];
    __shared__ float s_max[4];
    __shared__ u64   s_top[4 * TOPK];

    const float gx0 = gts[m * 4 + 0], gy0 = gts[m * 4 + 1];
    const float gx1 = gts[m * 4 + 2], gy1 = gts[m * 4 + 3];
    const float gcx = (gx0 + gx1) * 0.5f;
    const float gcy = (gy0 + gy1) * 0.5f;
    const int ci = min(GA - 1, max(0, (int)(gcx * (1.0f / CELL_A))));
    const int cj = min(GA - 1, max(0, (int)(gcy * (1.0f / CELL_A))));

    // ---- stage 1: rings 0..3 in parallel (wave w handles ring w).
    {
        const int r = wid;
        const int ncell = (r == 0) ? 1 : 8 * r;
        u32 myc = 0;
        float mymax = 0.f;
        for (int k = lane; k < ncell; k += 64) {
            int di = 0, dj = 0;
            if (r > 0) {
                int side = k / (2 * r), pos = k % (2 * r);
                if (side == 0)      { di = -r + pos; dj = -r; }
                else if (side == 1) { di = r;        dj = -r + pos; }
                else if (side == 2) { di = r - pos;  dj = r; }
                else                { di = -r;       dj = r - pos; }
            }
            int i = ci + di, j = cj + dj;
            if (i < 0 || i >= GA || j < 0 || j >= GA) continue;
            u32 cnt = cursA[j * GA + i];
            if (cnt) {
                myc += cnt;
                float x0 = i * CELL_A, x1 = x0 + CELL_A;
                float y0 = j * CELL_A, y1 = y0 + CELL_A;
                float dxm = fmaxf(gcx - x0, x1 - gcx);
                float dym = fmaxf(gcy - y0, y1 - gcy);
                mymax = fmaxf(mymax, dxm * dxm + dym * dym);
            }
        }
#pragma unroll
        for (int s2 = 1; s2 <= 32; s2 <<= 1) {
            myc += __shfl_xor(myc, s2, 64);
            mymax = fmaxf(mymax, __shfl_xor(mymax, s2, 64));
        }
        if (lane == 0) { s_cnt[wid] = myc; s_max[wid] = mymax; }
    }
    __syncthreads();

    // prefix over rings: include rings while cum<9 at ring entry (== include
    // through the first ring where cum crosses >=9) -- original semantics.
    u32 cum = 0;
    float maxd2 = 0.f;
#pragma unroll
    for (int r = 0; r < 4; ++r) {
        if (cum < TOPK) {
            cum += s_cnt[r];
            maxd2 = fmaxf(maxd2, s_max[r]);
        }
    }
    if (cum < TOPK) {   // statistically impossible here; exactness fallback.
        for (int r = 4; r < GA && cum < TOPK; ++r) {
            const int ncell = 8 * r;
            u32 myc = 0;
            float mymax = 0.f;
            for (int k = lane; k < ncell; k += 64) {
                int side = k / (2 * r), pos = k % (2 * r);
                int di, dj;
                if (side == 0)      { di = -r + pos; dj = -r; }
                else if (side == 1) { di = r;        dj = -r + pos; }
                else if (side == 2) { di = r - pos;  dj = r; }
                else                { di = -r;       dj = r - pos; }
                int i = ci + di, j = cj + dj;
                if (i < 0 || i >= GA || j < 0 || j >= GA) continue;
                u32 cnt = cursA[j * GA + i];
                if (cnt) {
                    myc += cnt;
                    float x0 = i * CELL_A, x1 = x0 + CELL_A;
                    float y0 = j * CELL_A, y1 = y0 + CELL_A;
                    float dxm = fmaxf(gcx - x0, x1 - gcx);
                    float dym = fmaxf(gcy - y0, y1 - gcy);
                    mymax = fmaxf(mymax, dxm * dxm + dym * dym);
                }
            }
#pragma unroll
            for (int s2 = 1; s2 <= 32; s2 <<= 1) {
                myc += __shfl_xor(myc, s2, 64);
                mymax = fmaxf(mymax, __shfl_xor(mymax, s2, 64));
            }
            cum += myc;          // identical across all 4 waves (same loads)
            maxd2 = fmaxf(maxd2, mymax);
        }
    }
    const float D2pad = maxd2 * 1.0001f + 1.0f;  // absorbs fp rounding + sqrt ties

    // ---- stage 2: exact top-9 over packed slots (+ overflow), block-wide.
    u64 kk[TOPK];
#pragma unroll
    for (int i = 0; i < TOPK; ++i) kk[i] = ~0ULL;

    const int rs = 1 + (int)(sqrtf(D2pad) * (1.0f / CELL_A));
    const int jlo = max(0, cj - rs), jhi = min(GA - 1, cj + rs);
    const int ilo = max(0, ci - rs), ihi = min(GA - 1, ci + rs);
    const int ncols  = ihi - ilo + 1;
    const int ncells = (jhi - jlo + 1) * ncols;
    for (int t = wid; t < ncells; t += 4) {      // cells strided over waves
        int j = jlo + t / ncols;
        int i = ilo + t % ncols;
        float y0 = j * CELL_A, y1 = y0 + CELL_A;
        float mdy = fmaxf(fmaxf(y0 - gcy, gcy - y1), 0.f);
        float x0 = i * CELL_A, x1 = x0 + CELL_A;
        float mdx = fmaxf(fmaxf(x0 - gcx, gcx - x1), 0.f);
        if (mdx * mdx + mdy * mdy > D2pad) continue;
        int c = j * GA + i;
        u32 cnt = min(cursA[c], (u32)CAPA);
        u32 base = (u32)c * CAPA;
        for (u32 tc = lane; tc < cnt; tc += 64) {   // slots strided over lanes
            float4 s = slotA[base + tc];
            float ddx = s.x - gcx, ddy = s.y - gcy;
            float d2 = ddx * ddx + ddy * ddy;
            if (d2 <= D2pad) {
                float d = sqrtf(d2);
                u64 key = ((u64)__float_as_uint(d) << 32) | __float_as_uint(s.z);
                if (key < kk[TOPK - 1]) {
                    u64 t2 = key;
#pragma unroll
                    for (int q = 0; q < TOPK; ++q) {
                        u64 lo = (kk[q] < t2) ? kk[q] : t2;
                        u64 hi = (kk[q] < t2) ? t2 : kk[q];
                        kk[q] = lo;
                        t2 = hi;
                    }
                }
            }
        }
    }
    {   // overflow anchors (exactness net; count is 0 on this data)
        u32 nov = min(ovfCnt[0], (u32)OVA);
        for (u32 tc = (u32)tid; tc < nov; tc += 256) {
            u32 n = ovAidx[tc];
            float2 cc = ovActr[tc];
            float ddx = cc.x - gcx, ddy = cc.y - gcy;
            float d2 = ddx * ddx + ddy * ddy;
            if (d2 <= D2pad) {
                float d = sqrtf(d2);
                u64 key = ((u64)__float_as_uint(d) << 32) | n;
                if (key < kk[TOPK - 1]) {
                    u64 t2 = key;
#pragma unroll
                    for (int q = 0; q < TOPK; ++q) {
                        u64 lo = (kk[q] < t2) ? kk[q] : t2;
                        u64 hi = (kk[q] < t2) ? t2 : kk[q];
                        kk[q] = lo;
                        t2 = hi;
                    }
                }
            }
        }
    }

    // ---- per-wave merge: 9 pop-min rounds (u64 butterfly)
    {
        u64 wv;
#pragma unroll
        for (int rd = 0; rd < TOPK; ++rd) {
            wv = kk[0];
#pragma unroll
            for (int s2 = 1; s2 <= 32; s2 <<= 1) {
                u64 o = __shfl_xor(wv, s2, 64);
                if (o < wv) wv = o;
            }
            if (lane == 0) s_top[wid * TOPK + rd] = wv;
            if (kk[0] == wv) {
#pragma unroll
                for (int q = 0; q < TOPK - 1; ++q) kk[q] = kk[q + 1];
                kk[TOPK - 1] = ~0ULL;
            }
        }
    }
    __syncthreads();

    // ---- cross-wave merge (wave 0 over the 36 survivors) + epilogue
    if (wid == 0) {
        u64 v = (lane < 4 * TOPK) ? s_top[lane] : ~0ULL;
        u64 wins[TOPK];
#pragma unroll
        for (int rd = 0; rd < TOPK; ++rd) {
            u64 wv = v;
#pragma unroll
            for (int s2 = 1; s2 <= 32; s2 <<= 1) {
                u64 o = __shfl_xor(wv, s2, 64);
                if (o < wv) wv = o;
            }
            wins[rd] = wv;
            if (v == wv) v = ~0ULL;
        }

        if (lane == 0) {
            const float area_g = (gx1 - gx0) * (gy1 - gy0);
            float vals[TOPK];
            float sum = 0.f;
#pragma unroll
            for (int r = 0; r < TOPK; ++r) {
                int idx = (int)(u32)(wins[r] & 0xffffffffULL);
                float4 a = a4[idx];
                float area_a = (a.z - a.x) * (a.w - a.y);
                float ltx = fmaxf(a.x, gx0), lty = fmaxf(a.y, gy0);
                float rbx = fminf(a.z, gx1), rby = fminf(a.w, gy1);
                float w2 = fmaxf(rbx - ltx, 0.f);
                float h2 = fmaxf(rby - lty, 0.f);
                float inter = w2 * h2;
                float uni = area_a + area_g - inter;
                float iou = inter / fmaxf(uni, 1e-12f);
                vals[r] = iou;
                sum += iou;
            }
            float mean = sum / 9.0f;
            float var = 0.f;
#pragma unroll
            for (int r = 0; r < TOPK; ++r) {
                float d2 = vals[r] - mean;
                var += d2 * d2;
            }
            float sd = sqrtf(var / 8.0f);   // ddof = 1
            thresh[m] = mean + sd;
        }
    }
}

// ===========================================================================
// Dispatch 4: assign. Original-order anchors (coalesced a4); per-anchor scan
// of its GT-cell PACKED box list (contiguous, L2-hot); gtBkt/thresh gathers
// only on inside-hits (~3 of 8 entries).
// ===========================================================================
__global__ __launch_bounds__(256) void atss_assign(
    const float4* __restrict__ a4, const float4* __restrict__ g4,
    const float* __restrict__ thresh,
    const u32* __restrict__ cursG, const float4* __restrict__ gtBox,
    const u32* __restrict__ gtBkt,
    const u32* __restrict__ ovfCnt, const u32* __restrict__ ovGidx,
    float* __restrict__ out_idx, float* __restrict__ out_iou, int N, int M)
{
    int n = blockIdx.x * 256 + threadIdx.x;
    if (n >= N) return;

    float4 a = a4[n];
    float area_a = (a.z - a.x) * (a.w - a.y);
    float cx = (a.x + a.z) * 0.5f;
    float cy = (a.y + a.w) * 0.5f;

    int ig = min(GG - 1, max(0, (int)(cx * (1.0f / CELL_G))));
    int jg = min(GG - 1, max(0, (int)(cy * (1.0f / CELL_G))));
    int cell = jg * GG + ig;

    u64 best = 0;   // ((m+1) << 32) | f32_bits(iou); 0 = unmatched
    u32 cnt = min(cursG[cell], (u32)CAPG);
    u32 base = (u32)cell * CAPG;
    for (u32 t2 = 0; t2 < cnt; ++t2) {
        float4 g = gtBox[base + t2];
        if (cx >= g.x && cx <= g.z && cy >= g.y && cy <= g.w) {
            int mi = (int)gtBkt[base + t2];
            float area_g = (g.z - g.x) * (g.w - g.y);
            float ltx = fmaxf(a.x, g.x), lty = fmaxf(a.y, g.y);
            float rbx = fminf(a.z, g.z), rby = fminf(a.w, g.w);
            float w = fmaxf(rbx - ltx, 0.f);
            float h = fmaxf(rby - lty, 0.f);
            float inter = w * h;
            float uni = area_a + area_g - inter;
            float iou = inter / fmaxf(uni, 1e-12f);
            if (iou >= thresh[mi]) {
                u64 cand = ((u64)(u32)(mi + 1) << 32) | __float_as_uint(iou);
                if (cand > best) best = cand;
            }
        }
    }
    {   // overflow GTs (exactness net; 0 on this data)
        u32 nog = min(ovfCnt[1], (u32)OVG);
        for (u32 t2 = 0; t2 < nog; ++t2) {
            int mi = (int)ovGidx[t2];
            float4 g = g4[mi];
            if (cx >= g.x && cx <= g.z && cy >= g.y && cy <= g.w) {
                float area_g = (g.z - g.x) * (g.w - g.y);
                float ltx = fmaxf(a.x, g.x), lty = fmaxf(a.y, g.y);
                float rbx = fminf(a.z, g.z), rby = fminf(a.w, g.w);
                float w = fmaxf(rbx - ltx, 0.f);
                float h = fmaxf(rby - lty, 0.f);
                float inter = w * h;
                float uni = area_a + area_g - inter;
                float iou = inter / fmaxf(uni, 1e-12f);
                if (iou >= thresh[mi]) {
                    u64 cand = ((u64)(u32)(mi + 1) << 32) | __float_as_uint(iou);
                    if (cand > best) best = cand;
                }
            }
        }
    }

    int mm = (int)(best >> 32) - 1;
    out_idx[n] = (float)mm;
    out_iou[n] = (mm >= 0) ? __uint_as_float((u32)best) : 0.f;
}

// ===========================================================================
// Fallback path (round-2, known-pass; needs only M floats of workspace)
// ===========================================================================
__global__ __launch_bounds__(256) void fb_centers(
    const float4* __restrict__ a4, float2* __restrict__ c2, int N)
{
    int n = blockIdx.x * 256 + threadIdx.x;
    if (n < N) {
        float4 a = a4[n];
        c2[n] = make_float2((a.x + a.z) * 0.5f, (a.y + a.w) * 0.5f);
    }
}

__global__ __launch_bounds__(256) void fb_thresh(
    const float4* __restrict__ a4, const float2* __restrict__ c2,
    const float* __restrict__ gts, float* __restrict__ thresh, int N)
{
    const int m = blockIdx.x;
    const int tid = threadIdx.x;
    const float gx0 = gts[m * 4 + 0], gy0 = gts[m * 4 + 1];
    const float gx1 = gts[m * 4 + 2], gy1 = gts[m * 4 + 3];
    const float gcx = (gx0 + gx1) * 0.5f;
    const float gcy = (gy0 + gy1) * 0.5f;

    float vmin = __builtin_inff();
    for (int n = tid; n < N; n += 512) {
        float2 c = c2[n];
        float dx = c.x - gcx, dy = c.y - gcy;
        vmin = fminf(vmin, dx * dx + dy * dy);
    }
    float v = vmin, w = 0.f;
#pragma unroll
    for (int r = 0; r < TOPK; ++r) {
        float t = v;
#pragma unroll
        for (int s = 1; s <= 32; s <<= 1) t = fminf(t, __shfl_xor(t, s, 64));
        w = t;
        if (v == w) v = __builtin_inff();
    }
    const float T = sqrtf(w) * 1.0001f + 1e-6f;

    u64 k[TOPK];
#pragma unroll
    for (int i = 0; i < TOPK; ++i) k[i] = ~0ULL;
    for (int n = tid; n < N; n += 256) {
        float2 c = c2[n];
        float dx = c.x - gcx, dy = c.y - gcy;
        float d = sqrtf(dx * dx + dy * dy);
        if (d <= T) {
            u64 key = ((u64)__float_as_uint(d) << 32) | (unsigned)n;
            if (key < k[TOPK - 1]) {
                u64 t = key;
#pragma unroll
                for (int i = 0; i < TOPK; ++i) {
                    u64 lo = (k[i] < t) ? k[i] : t;
                    u64 hi = (k[i] < t) ? t : k[i];
                    k[i] = lo;
                    t = hi;
                }
            }
        }
    }
    __shared__ u64 red[256];
    __shared__ int top9[TOPK];
#pragma unroll 1
    for (int r = 0; r < TOPK; ++r) {
        red[tid] = k[0];
        __syncthreads();
        for (int s = 128; s > 0; s >>= 1) {
            if (tid < s) {
                u64 o = red[tid + s];
                if (o < red[tid]) red[tid] = o;
            }
            __syncthreads();
        }
        u64 win = red[0];
        if (tid == 0) top9[r] = (int)(unsigned)(win & 0xffffffffULL);
        __syncthreads();
        if (k[0] == win) {
#pragma unroll
            for (int i = 0; i < TOPK - 1; ++i) k[i] = k[i + 1];
            k[TOPK - 1] = ~0ULL;
        }
    }
    if (tid == 0) {
        const float area_g = (gx1 - gx0) * (gy1 - gy0);
        float vals[TOPK];
        float s = 0.f;
#pragma unroll
        for (int r = 0; r < TOPK; ++r) {
            float4 a = a4[top9[r]];
            float area_a = (a.z - a.x) * (a.w - a.y);
            float ltx = fmaxf(a.x, gx0), lty = fmaxf(a.y, gy0);
            float rbx = fminf(a.z, gx1), rby = fminf(a.w, gy1);
            float w2 = fmaxf(rbx - ltx, 0.f);
            float h2 = fmaxf(rby - lty, 0.f);
            float inter = w2 * h2;
            float uni = area_a + area_g - inter;
            float iou = inter / fmaxf(uni, 1e-12f);
            vals[r] = iou;
            s += iou;
        }
        float mean = s / 9.0f;
        float var = 0.f;
#pragma unroll
        for (int r = 0; r < TOPK; ++r) {
            float d2 = vals[r] - mean;
            var += d2 * d2;
        }
        thresh[m] = mean + sqrtf(var / 8.0f);
    }
}

__global__ __launch_bounds__(256) void fb_assign(
    const float4* __restrict__ a4, const float4* __restrict__ g4,
    const float* __restrict__ thresh,
    float* __restrict__ out_idx, float* __restrict__ out_iou, int N, int M)
{
    extern __shared__ char smem[];
    float4* sg = (float4*)smem;
    float2* se = (float2*)(smem + (size_t)M * 16);
    for (int i = threadIdx.x; i < M; i += 256) {
        float4 g = g4[i];
        sg[i] = g;
        se[i] = make_float2((g.z - g.x) * (g.w - g.y), thresh[i]);
    }
    __syncthreads();
    int n = blockIdx.x * 256 + threadIdx.x;
    if (n >= N) return;
    float4 a = a4[n];
    float area_a = (a.z - a.x) * (a.w - a.y);
    float cx = (a.x + a.z) * 0.5f;
    float cy = (a.y + a.w) * 0.5f;
    u64 best = 0;
    for (int mi = 0; mi < M; ++mi) {
        float4 g = sg[mi];
        if (cx >= g.x && cx <= g.z && cy >= g.y && cy <= g.w) {
            float2 e = se[mi];
            float ltx = fmaxf(a.x, g.x), lty = fmaxf(a.y, g.y);
            float rbx = fminf(a.z, g.z), rby = fminf(a.w, g.w);
            float w = fmaxf(rbx - ltx, 0.f);
            float h = fmaxf(rby - lty, 0.f);
            float inter = w * h;
            float uni = area_a + e.x - inter;
            float iou = inter / fmaxf(uni, 1e-12f);
            if (iou >= e.y)
                best = ((u64)(u32)(mi + 1) << 32) | __float_as_uint(iou);
        }
    }
    int mm = (int)(best >> 32) - 1;
    out_idx[n] = (float)mm;
    out_iou[n] = (mm >= 0) ? __uint_as_float((u32)best) : 0.f;
}

// ===========================================================================
extern "C" void kernel_launch(void* const* d_in, const int* in_sizes, int n_in,
                              void* d_out, int out_size, void* d_ws, size_t ws_size,
                              hipStream_t stream) {
    const float4* a4 = (const float4*)d_in[0];
    const float4* g4 = (const float4*)d_in[1];
    const float* gts = (const float*)d_in[1];
    const int N = in_sizes[0] / 4;   // 120000
    const int M = in_sizes[1] / 4;   // 800

    // ws layout (u32 units); cursA/cursG/ovfCnt contiguous for one zero pass
    const size_t oCursA  = 0;                          // NCA
    const size_t oCursG  = oCursA + NCA;               // NCG
    const size_t oOvfCnt = oCursG + NCG;               // 2
    const size_t oThresh = oOvfCnt + 2;                // M
    size_t oSlotA = oThresh + (size_t)M;
    oSlotA = (oSlotA + 3) & ~(size_t)3;                // 16B align for float4
    const size_t oGtBox  = oSlotA + 4 * (size_t)NCA * CAPA;   // 16B-aligned
    const size_t oGtBkt  = oGtBox + 4 * (size_t)NCG * CAPG;
    const size_t oOvAidx = oGtBkt + (size_t)NCG * CAPG;
    size_t oOvActr = oOvAidx + OVA;
    oOvActr = (oOvActr + 1) & ~(size_t)1;              // 8B align
    const size_t oOvGidx = oOvActr + 2 * (size_t)OVA;
    const size_t needBytes = (oOvGidx + OVG) * sizeof(u32);

    if (ws_size >= needBytes) {
        u32* w = (u32*)d_ws;
        u32* cursA    = w + oCursA;
        u32* cursG    = w + oCursG;
        u32* ovfCnt   = w + oOvfCnt;
        float* thr    = (float*)(w + oThresh);
        float4* slotA = (float4*)(w + oSlotA);
        float4* gtBox = (float4*)(w + oGtBox);
        u32* gtBkt    = w + oGtBkt;
        u32* ovAidx   = w + oOvAidx;
        float2* ovActr= (float2*)(w + oOvActr);
        u32* ovGidx   = w + oOvGidx;

        const int nZero = NCA + NCG + 2;   // cursors + overflow counters
        zero_counts<<<(nZero + 255) / 256, 256, 0, stream>>>(cursA, nZero);
        bucket_insert<<<(N + M + 255) / 256, 256, 0, stream>>>(
            a4, g4, cursA, cursG, ovfCnt, slotA, gtBox, gtBkt,
            ovAidx, ovActr, ovGidx, N, M);
        atss_query<<<M, 256, 0, stream>>>(
            a4, gts, cursA, slotA, ovfCnt, ovAidx, ovActr, thr, M);
        atss_assign<<<(N + 255) / 256, 256, 0, stream>>>(
            a4, g4, thr, cursG, gtBox, gtBkt, ovfCnt, ovGidx,
            (float*)d_out, (float*)d_out + N, N, M);
    } else {
        // fallback: round-2 path
        float* thr = (float*)d_ws;
        float2* centers = (float2*)d_out;
        fb_centers<<<(N + 255) / 256, 256, 0, stream>>>(a4, centers, N);
        fb_thresh<<<M, 256, 0, stream>>>(a4, (const float2*)centers, gts, thr, N);
        size_t lds = (size_t)M * 24;
        fb_assign<<<(N + 255) / 256, 256, lds, stream>>>(
            a4, g4, thr, (float*)d_out, (float*)d_out + N, N, M);
    }
}